// Round 1
// baseline (159.583 us; speedup 1.0000x reference)
//
#include <hip/hip_runtime.h>
#include <hip/hip_bf16.h>
#include <math.h>

#define Bn 8
#define Tn 1024
#define Vn 2048

typedef __attribute__((ext_vector_type(8))) __bf16 bf16x8;
typedef __attribute__((ext_vector_type(4))) float floatx4;

// ---------------- K0a: E[d] = exp(vw[d]); Cinv[t] = 1 / prefix_sum(E) ----------------
__global__ __launch_bounds__(1024) void k_prep(const float* __restrict__ vw,
                                               float* __restrict__ E,
                                               float* __restrict__ Cinv) {
    __shared__ float sc[Tn];
    int tid = threadIdx.x;
    float e = __expf(vw[tid]);
    E[tid] = e;
    sc[tid] = e;
    __syncthreads();
    for (int off = 1; off < Tn; off <<= 1) {
        float add = (tid >= off) ? sc[tid - off] : 0.0f;
        __syncthreads();
        sc[tid] += add;
        __syncthreads();
    }
    Cinv[tid] = 1.0f / sc[tid];  // inclusive scan -> C[t]
}

// ---------------- K0b: BT[s][k] = (k<=s) ? bf16(E[s-k]*Cinv[s]) : 0 ----------------
__global__ __launch_bounds__(256) void k_bt(const float* __restrict__ E,
                                            const float* __restrict__ Cinv,
                                            __hip_bfloat16* __restrict__ BT) {
    int s = blockIdx.x;
    int tid = threadIdx.x;
    float cinv = Cinv[s];
    int k0 = tid * 4;
    ushort u[4];
#pragma unroll
    for (int j = 0; j < 4; ++j) {
        int k = k0 + j;
        float v = (k <= s) ? E[s - k] * cinv : 0.0f;
        __hip_bfloat16 h = __float2bfloat16(v);
        u[j] = *reinterpret_cast<ushort*>(&h);
    }
    *reinterpret_cast<ushort4*>(&BT[(size_t)s * Tn + k0]) = make_ushort4(u[0], u[1], u[2], u[3]);
}

// ---------------- K1: Agath[b][t][k] = bf16(W[idx[b,t], idx[b,k]]) ----------------
__global__ __launch_bounds__(256) void k_gather(const int* __restrict__ idx,
                                                const float* __restrict__ W,
                                                __hip_bfloat16* __restrict__ A) {
    int b = blockIdx.y, t = blockIdx.x, tid = threadIdx.x;
    int r = idx[b * Tn + t];                       // wave-uniform (scalarized)
    const float* Wr = W + (size_t)r * Vn;
    int4 c4 = *reinterpret_cast<const int4*>(&idx[b * Tn + tid * 4]);
    ushort u[4];
    __hip_bfloat16 h;
    h = __float2bfloat16(Wr[c4.x]); u[0] = *reinterpret_cast<ushort*>(&h);
    h = __float2bfloat16(Wr[c4.y]); u[1] = *reinterpret_cast<ushort*>(&h);
    h = __float2bfloat16(Wr[c4.z]); u[2] = *reinterpret_cast<ushort*>(&h);
    h = __float2bfloat16(Wr[c4.w]); u[3] = *reinterpret_cast<ushort*>(&h);
    *reinterpret_cast<ushort4*>(&A[((size_t)(b * Tn + t)) * Tn + tid * 4]) =
        make_ushort4(u[0], u[1], u[2], u[3]);
}

// ---------------- K2: per-b GEMM a2raw[b][t][s] = sum_k A[b][t][k] * BT[s][k] ----------------
#define TM 128
#define TN 128
#define BK 32
#define LDP 40  // padded LDS row (bf16 elems); 80 B = 16B-aligned, 2-way banks (free)

__global__ __launch_bounds__(256) void k_gemm(const __hip_bfloat16* __restrict__ A,
                                              const __hip_bfloat16* __restrict__ BT,
                                              float* __restrict__ Cout) {
    __shared__ __align__(16) __hip_bfloat16 As[TM][LDP];
    __shared__ __align__(16) __hip_bfloat16 Bs[TN][LDP];
    int b = blockIdx.z;
    int m0 = blockIdx.y * TM;
    int n0 = blockIdx.x * TN;
    int tid = threadIdx.x;
    int wave = tid >> 6, lane = tid & 63;
    int wm = (wave >> 1) * 64, wn = (wave & 1) * 64;
    int lrow = lane & 15, quad = lane >> 4;

    const __hip_bfloat16* Ab = A + (size_t)b * Tn * Tn;

    floatx4 acc[4][4];
#pragma unroll
    for (int i = 0; i < 4; ++i)
#pragma unroll
        for (int j = 0; j < 4; ++j) acc[i][j] = (floatx4){0.f, 0.f, 0.f, 0.f};

    for (int k0 = 0; k0 < Tn; k0 += BK) {
#pragma unroll
        for (int i = 0; i < 2; ++i) {  // 512 chunks of 8 bf16 per tile, 2 per thread
            int ch = tid + i * 256;
            int r = ch >> 2, c = (ch & 3) * 8;
            *reinterpret_cast<uint4*>(&As[r][c]) =
                *reinterpret_cast<const uint4*>(&Ab[(size_t)(m0 + r) * Tn + k0 + c]);
            *reinterpret_cast<uint4*>(&Bs[r][c]) =
                *reinterpret_cast<const uint4*>(&BT[(size_t)(n0 + r) * Tn + k0 + c]);
        }
        __syncthreads();
        bf16x8 af[4], bfr[4];
#pragma unroll
        for (int mi = 0; mi < 4; ++mi)
            af[mi] = *reinterpret_cast<const bf16x8*>(&As[wm + mi * 16 + lrow][quad * 8]);
#pragma unroll
        for (int ni = 0; ni < 4; ++ni)
            bfr[ni] = *reinterpret_cast<const bf16x8*>(&Bs[wn + ni * 16 + lrow][quad * 8]);
#pragma unroll
        for (int mi = 0; mi < 4; ++mi)
#pragma unroll
            for (int ni = 0; ni < 4; ++ni)
                acc[mi][ni] = __builtin_amdgcn_mfma_f32_16x16x32_bf16(af[mi], bfr[ni],
                                                                      acc[mi][ni], 0, 0, 0);
        __syncthreads();
    }

    float* Cb = Cout + (size_t)b * Tn * Tn;
#pragma unroll
    for (int mi = 0; mi < 4; ++mi)
#pragma unroll
        for (int ni = 0; ni < 4; ++ni)
#pragma unroll
            for (int r = 0; r < 4; ++r) {
                int row = m0 + wm + mi * 16 + quad * 4 + r;  // C/D: row = quad*4+reg
                int col = n0 + wn + ni * 16 + lrow;          //      col = lane&15
                Cb[(size_t)row * Tn + col] = acc[mi][ni][r];
            }
}

// ---------------- K3: softmax over s<=t, scatter-add into logits[b,t,:] ----------------
__global__ __launch_bounds__(256) void k_softscat(const float* __restrict__ a2raw,
                                                  const int* __restrict__ idx,
                                                  float* __restrict__ out) {
    __shared__ float sh[Vn];
    __shared__ float red[8];
    int t = blockIdx.x, b = blockIdx.y, tid = threadIdx.x;
    int wave = tid >> 6, lane = tid & 63;
#pragma unroll
    for (int i = 0; i < Vn / 256; ++i) sh[tid + i * 256] = 0.0f;

    const float* row = a2raw + ((size_t)b * Tn + t) * Tn;
    float4 v4 = *reinterpret_cast<const float4*>(&row[tid * 4]);
    int4 c4 = *reinterpret_cast<const int4*>(&idx[b * Tn + tid * 4]);
    int s0 = tid * 4;
    float v[4] = {v4.x, v4.y, v4.z, v4.w};
    float m = -INFINITY;
#pragma unroll
    for (int j = 0; j < 4; ++j) {
        if (s0 + j > t) v[j] = -INFINITY;
        m = fmaxf(m, v[j]);
    }
#pragma unroll
    for (int off = 32; off > 0; off >>= 1) m = fmaxf(m, __shfl_xor(m, off));
    if (lane == 0) red[wave] = m;
    __syncthreads();  // also covers sh zeroing
    m = fmaxf(fmaxf(red[0], red[1]), fmaxf(red[2], red[3]));
    float e[4];
    float lsum = 0.f;
#pragma unroll
    for (int j = 0; j < 4; ++j) {
        e[j] = (s0 + j <= t) ? __expf(v[j] - m) : 0.0f;
        lsum += e[j];
    }
#pragma unroll
    for (int off = 32; off > 0; off >>= 1) lsum += __shfl_xor(lsum, off);
    if (lane == 0) red[4 + wave] = lsum;
    __syncthreads();
    float inv = 1.0f / (red[4] + red[5] + red[6] + red[7]);
    int c[4] = {c4.x, c4.y, c4.z, c4.w};
#pragma unroll
    for (int j = 0; j < 4; ++j)
        if (s0 + j <= t) atomicAdd(&sh[c[j]], e[j] * inv);
    __syncthreads();
    float* orow = out + ((size_t)b * Tn + t) * Vn;
#pragma unroll
    for (int i = 0; i < Vn / (256 * 4); ++i)
        *reinterpret_cast<float4*>(&orow[(tid + i * 256) * 4]) =
            *reinterpret_cast<const float4*>(&sh[(tid + i * 256) * 4]);
}

extern "C" void kernel_launch(void* const* d_in, const int* in_sizes, int n_in,
                              void* d_out, int out_size, void* d_ws, size_t ws_size,
                              hipStream_t stream) {
    const int* idx = (const int*)d_in[0];
    const float* vw = (const float*)d_in[1];
    const float* W = (const float*)d_in[2];
    float* out = (float*)d_out;
    char* ws = (char*)d_ws;

    float* E = (float*)(ws);                                   // 4 KB
    float* Cinv = (float*)(ws + 4096);                         // 4 KB
    __hip_bfloat16* BT = (__hip_bfloat16*)(ws + 8192);         // 2 MB
    __hip_bfloat16* Abf = (__hip_bfloat16*)(ws + 2105344);     // 16 MB
    float* a2raw = (float*)(ws + 18882560);                    // 33.5 MB

    k_prep<<<1, 1024, 0, stream>>>(vw, E, Cinv);
    k_bt<<<dim3(Tn), 256, 0, stream>>>(E, Cinv, BT);
    k_gather<<<dim3(Tn, Bn), 256, 0, stream>>>(idx, W, Abf);
    k_gemm<<<dim3(Tn / TN, Tn / TM, Bn), 256, 0, stream>>>(Abf, BT, a2raw);
    k_softscat<<<dim3(Tn, Bn), 256, 0, stream>>>(a2raw, idx, out);
}

// Round 2
// 149.714 us; speedup vs baseline: 1.0659x; 1.0659x over previous
//
#include <hip/hip_runtime.h>
#include <hip/hip_bf16.h>
#include <math.h>

#define Bn 8
#define Tn 1024
#define Vn 2048

typedef __attribute__((ext_vector_type(8))) __bf16 bf16x8;
typedef __attribute__((ext_vector_type(4))) float floatx4;

// ---------------- K0: fused prep+BT. Block s: C[s]=sum_{d<=s}exp(vw[d]);
// BT[s][k] = (k<=s) ? bf16(exp(vw[s-k])/C[s]) : 0 ----------------
__global__ __launch_bounds__(256) void k_bt(const float* __restrict__ vw,
                                            __hip_bfloat16* __restrict__ BT) {
    __shared__ float red[4];
    int s = blockIdx.x;
    int tid = threadIdx.x;
    int wave = tid >> 6, lane = tid & 63;
    // masked sum: C[s] = sum_{d<=s} exp(vw[d])
    float part = 0.0f;
#pragma unroll
    for (int i = 0; i < 4; ++i) {
        int d = tid + i * 256;
        if (d <= s) part += __expf(vw[d]);
    }
#pragma unroll
    for (int off = 32; off > 0; off >>= 1) part += __shfl_xor(part, off);
    if (lane == 0) red[wave] = part;
    __syncthreads();
    float cinv = 1.0f / (red[0] + red[1] + red[2] + red[3]);

    int k0 = tid * 4;
    ushort u[4];
#pragma unroll
    for (int j = 0; j < 4; ++j) {
        int k = k0 + j;
        float v = (k <= s) ? __expf(vw[s - k]) * cinv : 0.0f;
        __hip_bfloat16 h = __float2bfloat16(v);
        u[j] = *reinterpret_cast<ushort*>(&h);
    }
    *reinterpret_cast<ushort4*>(&BT[(size_t)s * Tn + k0]) = make_ushort4(u[0], u[1], u[2], u[3]);
}

// ---------------- K1: Agath[b][t][k] = bf16(W[idx[b,t], idx[b,k]]) ----------------
__global__ __launch_bounds__(256) void k_gather(const int* __restrict__ idx,
                                                const float* __restrict__ W,
                                                __hip_bfloat16* __restrict__ A) {
    int b = blockIdx.y, t = blockIdx.x, tid = threadIdx.x;
    int r = idx[b * Tn + t];                       // wave-uniform (scalarized)
    const float* Wr = W + (size_t)r * Vn;
    int4 c4 = *reinterpret_cast<const int4*>(&idx[b * Tn + tid * 4]);
    ushort u[4];
    __hip_bfloat16 h;
    h = __float2bfloat16(Wr[c4.x]); u[0] = *reinterpret_cast<ushort*>(&h);
    h = __float2bfloat16(Wr[c4.y]); u[1] = *reinterpret_cast<ushort*>(&h);
    h = __float2bfloat16(Wr[c4.z]); u[2] = *reinterpret_cast<ushort*>(&h);
    h = __float2bfloat16(Wr[c4.w]); u[3] = *reinterpret_cast<ushort*>(&h);
    *reinterpret_cast<ushort4*>(&A[((size_t)(b * Tn + t)) * Tn + tid * 4]) =
        make_ushort4(u[0], u[1], u[2], u[3]);
}

// ---------------- K2: per-b lower-triangle GEMM, K-trimmed ----------------
#define TM 128
#define TN 128
#define BK 32
#define LDP 40  // padded LDS row (bf16 elems); 80 B, 2-way banks (free)
#define NTILES 36

// heavy-first tile order: ni descending, mi = ni..7
__device__ const int TILE_MI[NTILES] = {7, 6,7, 5,6,7, 4,5,6,7, 3,4,5,6,7,
                                        2,3,4,5,6,7, 1,2,3,4,5,6,7, 0,1,2,3,4,5,6,7};
__device__ const int TILE_NI[NTILES] = {7, 6,6, 5,5,5, 4,4,4,4, 3,3,3,3,3,
                                        2,2,2,2,2,2, 1,1,1,1,1,1,1, 0,0,0,0,0,0,0,0};

__global__ __launch_bounds__(256) void k_gemm(const __hip_bfloat16* __restrict__ A,
                                              const __hip_bfloat16* __restrict__ BT,
                                              float* __restrict__ Cout) {
    __shared__ __align__(16) __hip_bfloat16 As[TM][LDP];
    __shared__ __align__(16) __hip_bfloat16 Bs[TN][LDP];
    int b = blockIdx.x;               // batch fastest -> heavy tiles of all b start first
    int tl = blockIdx.y;
    int mi = TILE_MI[tl], ni = TILE_NI[tl];
    int m0 = mi * TM;
    int n0 = ni * TN;
    int Kmax = (ni + 1) * TN;         // BT[s][k]==0 for k>s covers the rest exactly
    int tid = threadIdx.x;
    int wave = tid >> 6, lane = tid & 63;
    int wm = (wave >> 1) * 64, wn = (wave & 1) * 64;
    int lrow = lane & 15, quad = lane >> 4;

    const __hip_bfloat16* Ab = A + (size_t)b * Tn * Tn;

    floatx4 acc[4][4];
#pragma unroll
    for (int i = 0; i < 4; ++i)
#pragma unroll
        for (int j = 0; j < 4; ++j) acc[i][j] = (floatx4){0.f, 0.f, 0.f, 0.f};

    for (int k0 = 0; k0 < Kmax; k0 += BK) {
#pragma unroll
        for (int i = 0; i < 2; ++i) {  // 512 chunks of 8 bf16 per tile, 2 per thread
            int ch = tid + i * 256;
            int r = ch >> 2, c = (ch & 3) * 8;
            *reinterpret_cast<uint4*>(&As[r][c]) =
                *reinterpret_cast<const uint4*>(&Ab[(size_t)(m0 + r) * Tn + k0 + c]);
            *reinterpret_cast<uint4*>(&Bs[r][c]) =
                *reinterpret_cast<const uint4*>(&BT[(size_t)(n0 + r) * Tn + k0 + c]);
        }
        __syncthreads();
        bf16x8 af[4], bfr[4];
#pragma unroll
        for (int mi2 = 0; mi2 < 4; ++mi2)
            af[mi2] = *reinterpret_cast<const bf16x8*>(&As[wm + mi2 * 16 + lrow][quad * 8]);
#pragma unroll
        for (int ni2 = 0; ni2 < 4; ++ni2)
            bfr[ni2] = *reinterpret_cast<const bf16x8*>(&Bs[wn + ni2 * 16 + lrow][quad * 8]);
#pragma unroll
        for (int mi2 = 0; mi2 < 4; ++mi2)
#pragma unroll
            for (int ni2 = 0; ni2 < 4; ++ni2)
                acc[mi2][ni2] = __builtin_amdgcn_mfma_f32_16x16x32_bf16(af[mi2], bfr[ni2],
                                                                        acc[mi2][ni2], 0, 0, 0);
        __syncthreads();
    }

    float* Cb = Cout + (size_t)b * Tn * Tn;
#pragma unroll
    for (int mi2 = 0; mi2 < 4; ++mi2)
#pragma unroll
        for (int ni2 = 0; ni2 < 4; ++ni2)
#pragma unroll
            for (int r = 0; r < 4; ++r) {
                int row = m0 + wm + mi2 * 16 + quad * 4 + r;  // C/D: row = quad*4+reg
                int col = n0 + wn + ni2 * 16 + lrow;          //      col = lane&15
                Cb[(size_t)row * Tn + col] = acc[mi2][ni2][r];
            }
}

// ---------------- K3: softmax over s<=t, scatter-add into logits[b,t,:] ----------------
__global__ __launch_bounds__(256) void k_softscat(const float* __restrict__ a2raw,
                                                  const int* __restrict__ idx,
                                                  float* __restrict__ out) {
    __shared__ float sh[Vn];
    __shared__ float red[8];
    int t = blockIdx.x, b = blockIdx.y, tid = threadIdx.x;
    int wave = tid >> 6, lane = tid & 63;
#pragma unroll
    for (int i = 0; i < Vn / 256; ++i) sh[tid + i * 256] = 0.0f;

    const float* row = a2raw + ((size_t)b * Tn + t) * Tn;
    int s0 = tid * 4;
    float v[4] = {-INFINITY, -INFINITY, -INFINITY, -INFINITY};
    if (s0 <= t) {  // predicated: skip never-computed upper-triangle tiles
        float4 v4 = *reinterpret_cast<const float4*>(&row[s0]);
        v[0] = v4.x; v[1] = v4.y; v[2] = v4.z; v[3] = v4.w;
    }
    int4 c4 = *reinterpret_cast<const int4*>(&idx[b * Tn + s0]);
    float m = -INFINITY;
#pragma unroll
    for (int j = 0; j < 4; ++j) {
        if (s0 + j > t) v[j] = -INFINITY;
        m = fmaxf(m, v[j]);
    }
#pragma unroll
    for (int off = 32; off > 0; off >>= 1) m = fmaxf(m, __shfl_xor(m, off));
    if (lane == 0) red[wave] = m;
    __syncthreads();  // also covers sh zeroing
    m = fmaxf(fmaxf(red[0], red[1]), fmaxf(red[2], red[3]));
    float e[4];
    float lsum = 0.f;
#pragma unroll
    for (int j = 0; j < 4; ++j) {
        e[j] = (s0 + j <= t) ? __expf(v[j] - m) : 0.0f;
        lsum += e[j];
    }
#pragma unroll
    for (int off = 32; off > 0; off >>= 1) lsum += __shfl_xor(lsum, off);
    if (lane == 0) red[4 + wave] = lsum;
    __syncthreads();
    float inv = 1.0f / (red[4] + red[5] + red[6] + red[7]);
    int c[4] = {c4.x, c4.y, c4.z, c4.w};
#pragma unroll
    for (int j = 0; j < 4; ++j)
        if (s0 + j <= t) atomicAdd(&sh[c[j]], e[j] * inv);
    __syncthreads();
    float* orow = out + ((size_t)b * Tn + t) * Vn;
#pragma unroll
    for (int i = 0; i < Vn / (256 * 4); ++i)
        *reinterpret_cast<float4*>(&orow[(tid + i * 256) * 4]) =
            *reinterpret_cast<const float4*>(&sh[(tid + i * 256) * 4]);
}

extern "C" void kernel_launch(void* const* d_in, const int* in_sizes, int n_in,
                              void* d_out, int out_size, void* d_ws, size_t ws_size,
                              hipStream_t stream) {
    const int* idx = (const int*)d_in[0];
    const float* vw = (const float*)d_in[1];
    const float* W = (const float*)d_in[2];
    float* out = (float*)d_out;
    char* ws = (char*)d_ws;

    __hip_bfloat16* BT = (__hip_bfloat16*)(ws);                // 2 MB
    __hip_bfloat16* Abf = (__hip_bfloat16*)(ws + (2u << 20));  // 16 MB
    float* a2raw = (float*)(ws + (18u << 20));                 // 33.5 MB

    k_bt<<<dim3(Tn), 256, 0, stream>>>(vw, BT);
    k_gather<<<dim3(Tn, Bn), 256, 0, stream>>>(idx, W, Abf);
    k_gemm<<<dim3(Bn, NTILES), 256, 0, stream>>>(Abf, BT, a2raw);
    k_softscat<<<dim3(Tn, Bn), 256, 0, stream>>>(a2raw, idx, out);
}

// Round 3
// 138.199 us; speedup vs baseline: 1.1547x; 1.0833x over previous
//
#include <hip/hip_runtime.h>
#include <hip/hip_bf16.h>
#include <math.h>

#define Bn 8
#define Tn 1024
#define Vn 2048

typedef __attribute__((ext_vector_type(8))) __bf16 bf16x8;
typedef __attribute__((ext_vector_type(4))) float floatx4;

// ---------------- K0: fused prep+BT. Block s: C[s]=sum_{d<=s}exp(vw[d]);
// BT[s][k] = (k<=s) ? bf16(exp(vw[s-k])/C[s]) : 0 ----------------
__global__ __launch_bounds__(256) void k_bt(const float* __restrict__ vw,
                                            __hip_bfloat16* __restrict__ BT) {
    __shared__ float red[4];
    int s = blockIdx.x;
    int tid = threadIdx.x;
    int wave = tid >> 6, lane = tid & 63;
    float part = 0.0f;
#pragma unroll
    for (int i = 0; i < 4; ++i) {
        int d = tid + i * 256;
        if (d <= s) part += __expf(vw[d]);
    }
#pragma unroll
    for (int off = 32; off > 0; off >>= 1) part += __shfl_xor(part, off);
    if (lane == 0) red[wave] = part;
    __syncthreads();
    float cinv = 1.0f / (red[0] + red[1] + red[2] + red[3]);

    int k0 = tid * 4;
    ushort u[4];
#pragma unroll
    for (int j = 0; j < 4; ++j) {
        int k = k0 + j;
        float v = (k <= s) ? __expf(vw[s - k]) * cinv : 0.0f;
        __hip_bfloat16 h = __float2bfloat16(v);
        u[j] = *reinterpret_cast<ushort*>(&h);
    }
    *reinterpret_cast<ushort4*>(&BT[(size_t)s * Tn + k0]) = make_ushort4(u[0], u[1], u[2], u[3]);
}

// ---------------- K1: Agath[b][t][k] = bf16(W[idx[b,t], idx[b,k]]) via LDS row stage ----------------
__global__ __launch_bounds__(256) void k_gather(const int* __restrict__ idx,
                                                const float* __restrict__ W,
                                                __hip_bfloat16* __restrict__ A) {
    __shared__ float wrow[Vn];  // 8 KB: the full W row, staged coalesced
    int b = blockIdx.y, t = blockIdx.x, tid = threadIdx.x;
    int r = idx[b * Tn + t];  // block-uniform
    const float* Wr = W + (size_t)r * Vn;
#pragma unroll
    for (int i = 0; i < 2; ++i) {
        int o = (tid + i * 256) * 4;
        *reinterpret_cast<float4*>(&wrow[o]) = *reinterpret_cast<const float4*>(&Wr[o]);
    }
    int4 c4 = *reinterpret_cast<const int4*>(&idx[b * Tn + tid * 4]);
    __syncthreads();
    ushort u[4];
    __hip_bfloat16 h;
    h = __float2bfloat16(wrow[c4.x]); u[0] = *reinterpret_cast<ushort*>(&h);
    h = __float2bfloat16(wrow[c4.y]); u[1] = *reinterpret_cast<ushort*>(&h);
    h = __float2bfloat16(wrow[c4.z]); u[2] = *reinterpret_cast<ushort*>(&h);
    h = __float2bfloat16(wrow[c4.w]); u[3] = *reinterpret_cast<ushort*>(&h);
    *reinterpret_cast<ushort4*>(&A[((size_t)(b * Tn + t)) * Tn + tid * 4]) =
        make_ushort4(u[0], u[1], u[2], u[3]);
}

// ---------------- K2: per-b lower-triangle GEMM, K-trimmed + 2-way split-K ----------------
#define TM 128
#define TN 128
#define BK 32
#define LDP 40  // padded LDS row (bf16); 80 B, 2-way banks (free)
#define NCHUNK 46

// heavy-first chunk list: (mi, ni, k-iter range [K0,K1), part). K iters in BK units.
__device__ const signed char CH_MI[NCHUNK] = {7,7,6,7,5,6,7,4,5,6,7,3,4,5,6,7,
                                              6,7,2,3,4,5,6,7,
                                              5,6,7,1,2,3,4,5,6,7,
                                              4,5,6,7,0,1,2,3,4,5,6,7};
__device__ const signed char CH_NI[NCHUNK] = {7,7,6,6,5,5,5,4,4,4,4,3,3,3,3,3,
                                              6,6,2,2,2,2,2,2,
                                              5,5,5,1,1,1,1,1,1,1,
                                              4,4,4,4,0,0,0,0,0,0,0,0};
__device__ const signed char CH_K0[NCHUNK] = {0,16,0,0,0,0,0,0,0,0,0,0,0,0,0,0,
                                              16,16,0,0,0,0,0,0,
                                              16,16,16,0,0,0,0,0,0,0,
                                              16,16,16,16,0,0,0,0,0,0,0,0};
__device__ const signed char CH_K1[NCHUNK] = {16,32,16,16,16,16,16,16,16,16,16,16,16,16,16,16,
                                              28,28,12,12,12,12,12,12,
                                              24,24,24,8,8,8,8,8,8,8,
                                              20,20,20,20,4,4,4,4,4,4,4,4};
__device__ const signed char CH_P[NCHUNK]  = {0,1,0,0,0,0,0,0,0,0,0,0,0,0,0,0,
                                              1,1,0,0,0,0,0,0,
                                              1,1,1,0,0,0,0,0,0,0,
                                              1,1,1,1,0,0,0,0,0,0,0,0};

__global__ __launch_bounds__(256) void k_gemm(const __hip_bfloat16* __restrict__ A,
                                              const __hip_bfloat16* __restrict__ BT,
                                              float* __restrict__ part0,
                                              float* __restrict__ part1) {
    __shared__ __align__(16) __hip_bfloat16 As[TM][LDP];
    __shared__ __align__(16) __hip_bfloat16 Bs[TN][LDP];
    int b = blockIdx.x;  // batch fastest -> heavy chunks of all b dispatched first
    int cidx = blockIdx.y;
    int mi = CH_MI[cidx], ni = CH_NI[cidx];
    int ki0 = CH_K0[cidx], ki1 = CH_K1[cidx];
    int m0 = mi * TM, n0 = ni * TN;
    int tid = threadIdx.x;
    int wave = tid >> 6, lane = tid & 63;
    int wm = (wave >> 1) * 64, wn = (wave & 1) * 64;
    int lrow = lane & 15, quad = lane >> 4;

    const __hip_bfloat16* Ab = A + (size_t)b * Tn * Tn;

    floatx4 acc[4][4];
#pragma unroll
    for (int i = 0; i < 4; ++i)
#pragma unroll
        for (int j = 0; j < 4; ++j) acc[i][j] = (floatx4){0.f, 0.f, 0.f, 0.f};

    for (int ki = ki0; ki < ki1; ++ki) {
        int k0 = ki * BK;
#pragma unroll
        for (int i = 0; i < 2; ++i) {
            int ch = tid + i * 256;
            int r = ch >> 2, c = (ch & 3) * 8;
            *reinterpret_cast<uint4*>(&As[r][c]) =
                *reinterpret_cast<const uint4*>(&Ab[(size_t)(m0 + r) * Tn + k0 + c]);
            *reinterpret_cast<uint4*>(&Bs[r][c]) =
                *reinterpret_cast<const uint4*>(&BT[(size_t)(n0 + r) * Tn + k0 + c]);
        }
        __syncthreads();
        bf16x8 af[4], bfr[4];
#pragma unroll
        for (int m = 0; m < 4; ++m)
            af[m] = *reinterpret_cast<const bf16x8*>(&As[wm + m * 16 + lrow][quad * 8]);
#pragma unroll
        for (int n = 0; n < 4; ++n)
            bfr[n] = *reinterpret_cast<const bf16x8*>(&Bs[wn + n * 16 + lrow][quad * 8]);
#pragma unroll
        for (int m = 0; m < 4; ++m)
#pragma unroll
            for (int n = 0; n < 4; ++n)
                acc[m][n] = __builtin_amdgcn_mfma_f32_16x16x32_bf16(af[m], bfr[n],
                                                                    acc[m][n], 0, 0, 0);
        __syncthreads();
    }

    float* Cb = (CH_P[cidx] ? part1 : part0) + (size_t)b * Tn * Tn;
#pragma unroll
    for (int m = 0; m < 4; ++m)
#pragma unroll
        for (int n = 0; n < 4; ++n)
#pragma unroll
            for (int r = 0; r < 4; ++r) {
                int row = m0 + wm + m * 16 + quad * 4 + r;  // C/D: row = quad*4+reg
                int col = n0 + wn + n * 16 + lrow;          //      col = lane&15
                Cb[(size_t)row * Tn + col] = acc[m][n][r];
            }
}

// ---------------- K3: softmax (no max shift; |a2|<0.2) over s<=t, scatter into logits ----------------
__global__ __launch_bounds__(256) void k_softscat(const float* __restrict__ part0,
                                                  const float* __restrict__ part1,
                                                  const int* __restrict__ idx,
                                                  float* __restrict__ out) {
    __shared__ float sh[Vn];
    __shared__ float red[4];
    int t = blockIdx.x, b = blockIdx.y, tid = threadIdx.x;
    int wave = tid >> 6, lane = tid & 63;
#pragma unroll
    for (int i = 0; i < Vn / 256; ++i) sh[tid + i * 256] = 0.0f;

    size_t rowoff = ((size_t)b * Tn + t) * Tn;
    int s0 = tid * 4;
    float v[4] = {0.f, 0.f, 0.f, 0.f};
    if (s0 <= t) {
        float4 v4 = *reinterpret_cast<const float4*>(&part0[rowoff + s0]);
        v[0] = v4.x; v[1] = v4.y; v[2] = v4.z; v[3] = v4.w;
        if (s0 >= 512) {  // split-K second partial exists exactly for s>=512
            float4 w4 = *reinterpret_cast<const float4*>(&part1[rowoff + s0]);
            v[0] += w4.x; v[1] += w4.y; v[2] += w4.z; v[3] += w4.w;
        }
    }
    int4 c4 = *reinterpret_cast<const int4*>(&idx[b * Tn + s0]);
    float e[4];
    float lsum = 0.f;
#pragma unroll
    for (int j = 0; j < 4; ++j) {
        e[j] = (s0 + j <= t) ? __expf(v[j]) : 0.0f;
        lsum += e[j];
    }
#pragma unroll
    for (int off = 32; off > 0; off >>= 1) lsum += __shfl_xor(lsum, off);
    if (lane == 0) red[wave] = lsum;
    __syncthreads();  // also covers sh zeroing
    float inv = 1.0f / (red[0] + red[1] + red[2] + red[3]);
    int c[4] = {c4.x, c4.y, c4.z, c4.w};
#pragma unroll
    for (int j = 0; j < 4; ++j)
        if (s0 + j <= t) atomicAdd(&sh[c[j]], e[j] * inv);
    __syncthreads();
    float* orow = out + ((size_t)b * Tn + t) * Vn;
#pragma unroll
    for (int i = 0; i < Vn / (256 * 4); ++i)
        *reinterpret_cast<float4*>(&orow[(tid + i * 256) * 4]) =
            *reinterpret_cast<const float4*>(&sh[(tid + i * 256) * 4]);
}

extern "C" void kernel_launch(void* const* d_in, const int* in_sizes, int n_in,
                              void* d_out, int out_size, void* d_ws, size_t ws_size,
                              hipStream_t stream) {
    const int* idx = (const int*)d_in[0];
    const float* vw = (const float*)d_in[1];
    const float* W = (const float*)d_in[2];
    float* out = (float*)d_out;
    char* ws = (char*)d_ws;

    __hip_bfloat16* BT = (__hip_bfloat16*)(ws);                 // 2 MB
    __hip_bfloat16* Abf = (__hip_bfloat16*)(ws + (2u << 20));   // 16 MB
    float* part0 = (float*)(ws + (18u << 20));                  // 33.6 MB
    float* part1 = (float*)(ws + (52u << 20));                  // 33.6 MB

    k_gather<<<dim3(Tn, Bn), 256, 0, stream>>>(idx, W, Abf);
    k_bt<<<dim3(Tn), 256, 0, stream>>>(vw, BT);
    k_gemm<<<dim3(Bn, NCHUNK), 256, 0, stream>>>(Abf, BT, part0, part1);
    k_softscat<<<dim3(Tn, Bn), 256, 0, stream>>>(part0, part1, idx, out);
}

// Round 4
// 136.282 us; speedup vs baseline: 1.1710x; 1.0141x over previous
//
#include <hip/hip_runtime.h>
#include <hip/hip_bf16.h>
#include <math.h>

#define Bn 8
#define Tn 1024
#define Vn 2048

typedef __attribute__((ext_vector_type(8))) __bf16 bf16x8;
typedef __attribute__((ext_vector_type(4))) float floatx4;

#define GLDS(gp, lp) \
    __builtin_amdgcn_global_load_lds( \
        (const __attribute__((address_space(1))) void*)(gp), \
        (__attribute__((address_space(3))) void*)(lp), 16, 0, 0)

// ---------------- K0: fused prep.
// blockIdx.y < Bn : gather  Abf[b][t][k] = bf16(W[idx[b,t], idx[b,k]])
// blockIdx.y == Bn: BT[s][k] = (k<=s) ? bf16(exp(vw[s-k])/C[s]) : 0,  C[s]=sum_{d<=s}exp(vw[d])
__global__ __launch_bounds__(256) void k_prep(const int* __restrict__ idx,
                                              const float* __restrict__ W,
                                              const float* __restrict__ vw,
                                              __hip_bfloat16* __restrict__ Abf,
                                              __hip_bfloat16* __restrict__ BT) {
    __shared__ float sbuf[Vn];  // gather: staged W row; bt: 4-float reduction scratch
    int tid = threadIdx.x;
    if (blockIdx.y == Bn) {
        int s = blockIdx.x;
        int wave = tid >> 6, lane = tid & 63;
        float part = 0.0f;
#pragma unroll
        for (int i = 0; i < 4; ++i) {
            int d = tid + i * 256;
            if (d <= s) part += __expf(vw[d]);
        }
#pragma unroll
        for (int off = 32; off > 0; off >>= 1) part += __shfl_xor(part, off);
        if (lane == 0) sbuf[wave] = part;
        __syncthreads();
        float cinv = 1.0f / (sbuf[0] + sbuf[1] + sbuf[2] + sbuf[3]);
        int k0 = tid * 4;
        ushort u[4];
#pragma unroll
        for (int j = 0; j < 4; ++j) {
            int k = k0 + j;
            float v = (k <= s) ? __expf(vw[s - k]) * cinv : 0.0f;
            __hip_bfloat16 h = __float2bfloat16(v);
            u[j] = *reinterpret_cast<ushort*>(&h);
        }
        *reinterpret_cast<ushort4*>(&BT[(size_t)s * Tn + k0]) =
            make_ushort4(u[0], u[1], u[2], u[3]);
    } else {
        int b = blockIdx.y, t = blockIdx.x;
        int r = idx[b * Tn + t];  // block-uniform
        const float* Wr = W + (size_t)r * Vn;
#pragma unroll
        for (int i = 0; i < 2; ++i) {
            int o = (tid + i * 256) * 4;
            *reinterpret_cast<float4*>(&sbuf[o]) = *reinterpret_cast<const float4*>(&Wr[o]);
        }
        int4 c4 = *reinterpret_cast<const int4*>(&idx[b * Tn + tid * 4]);
        __syncthreads();
        ushort u[4];
        __hip_bfloat16 h;
        h = __float2bfloat16(sbuf[c4.x]); u[0] = *reinterpret_cast<ushort*>(&h);
        h = __float2bfloat16(sbuf[c4.y]); u[1] = *reinterpret_cast<ushort*>(&h);
        h = __float2bfloat16(sbuf[c4.z]); u[2] = *reinterpret_cast<ushort*>(&h);
        h = __float2bfloat16(sbuf[c4.w]); u[3] = *reinterpret_cast<ushort*>(&h);
        *reinterpret_cast<ushort4*>(&Abf[((size_t)(b * Tn + t)) * Tn + tid * 4]) =
            make_ushort4(u[0], u[1], u[2], u[3]);
    }
}

// ---------------- K1: per-b lower-triangle GEMM, K-trim + 2-way split-K,
// global_load_lds(16B) staging into fragment-ordered LDS, BK=64 ----------------
#define TM 128
#define TN 128
#define NCHUNK 46

// chunk tables, K ranges in BK=64 units, heavy-first
__device__ const signed char CH_MI[NCHUNK] = {7,7,6,7,5,6,7,4,5,6,7,3,4,5,6,7,
                                              6,7,2,3,4,5,6,7,
                                              5,6,7,1,2,3,4,5,6,7,
                                              4,5,6,7,0,1,2,3,4,5,6,7};
__device__ const signed char CH_NI[NCHUNK] = {7,7,6,6,5,5,5,4,4,4,4,3,3,3,3,3,
                                              6,6,2,2,2,2,2,2,
                                              5,5,5,1,1,1,1,1,1,1,
                                              4,4,4,4,0,0,0,0,0,0,0,0};
__device__ const signed char CH_K0[NCHUNK] = {0,8,0,0,0,0,0,0,0,0,0,0,0,0,0,0,
                                              8,8,0,0,0,0,0,0,
                                              8,8,8,0,0,0,0,0,0,0,
                                              8,8,8,8,0,0,0,0,0,0,0,0};
__device__ const signed char CH_K1[NCHUNK] = {8,16,8,8,8,8,8,8,8,8,8,8,8,8,8,8,
                                              14,14,6,6,6,6,6,6,
                                              12,12,12,4,4,4,4,4,4,4,
                                              10,10,10,10,2,2,2,2,2,2,2,2};
__device__ const signed char CH_P[NCHUNK]  = {0,1,0,0,0,0,0,0,0,0,0,0,0,0,0,0,
                                              1,1,0,0,0,0,0,0,
                                              1,1,1,0,0,0,0,0,0,0,
                                              1,1,1,1,0,0,0,0,0,0,0,0};

__global__ __launch_bounds__(256) void k_gemm(const __hip_bfloat16* __restrict__ A,
                                              const __hip_bfloat16* __restrict__ BT,
                                              float* __restrict__ part0,
                                              float* __restrict__ part1) {
    // fragment-ordered LDS: chunk c (= h*8 + sub) holds 64 lanes x 16B;
    // lane l of chunk c = X[sub*16 + (l&15)][h*32 + (l>>4)*8 .. +8)
    __shared__ __align__(16) __hip_bfloat16 As[16 * 512];  // 16 KB
    __shared__ __align__(16) __hip_bfloat16 Bs[16 * 512];  // 16 KB
    int b = blockIdx.x;  // batch fastest -> heavy chunks dispatched first
    int cidx = blockIdx.y;
    int mi = CH_MI[cidx], ni = CH_NI[cidx];
    int ki0 = CH_K0[cidx], ki1 = CH_K1[cidx];
    int m0 = mi * TM, n0 = ni * TN;
    int tid = threadIdx.x;
    int wave = tid >> 6, lane = tid & 63;
    int lr = lane & 15, lq = lane >> 4;
    int wmsub = (wave >> 1) * 4, wnsub = (wave & 1) * 4;  // fragment sub-tile bases

    const __hip_bfloat16* Ab = A + (size_t)b * Tn * Tn;

    // per-wave staging assignment: chunks 4*wave .. 4*wave+3 for both A and B
    const __hip_bfloat16* aS[4];
    const __hip_bfloat16* bS[4];
    __hip_bfloat16* aD[4];
    __hip_bfloat16* bD[4];
#pragma unroll
    for (int j = 0; j < 4; ++j) {
        int c = wave * 4 + j;
        int sub = c & 7, h = c >> 3;
        aS[j] = Ab + (size_t)(m0 + sub * 16 + lr) * Tn + h * 32 + lq * 8;
        bS[j] = BT + (size_t)(n0 + sub * 16 + lr) * Tn + h * 32 + lq * 8;
        aD[j] = &As[c * 512];
        bD[j] = &Bs[c * 512];
    }

    floatx4 acc[4][4];
#pragma unroll
    for (int i = 0; i < 4; ++i)
#pragma unroll
        for (int j = 0; j < 4; ++j) acc[i][j] = (floatx4){0.f, 0.f, 0.f, 0.f};

    for (int ki = ki0; ki < ki1; ++ki) {
        int ko = ki * 64;
#pragma unroll
        for (int j = 0; j < 4; ++j) {
            GLDS(aS[j] + ko, aD[j]);
            GLDS(bS[j] + ko, bD[j]);
        }
        __syncthreads();
        bf16x8 af[2][4], bfr[2][4];
#pragma unroll
        for (int h = 0; h < 2; ++h) {
#pragma unroll
            for (int m = 0; m < 4; ++m)
                af[h][m] = *reinterpret_cast<const bf16x8*>(
                    &As[(h * 8 + wmsub + m) * 512 + lane * 8]);
#pragma unroll
            for (int n = 0; n < 4; ++n)
                bfr[h][n] = *reinterpret_cast<const bf16x8*>(
                    &Bs[(h * 8 + wnsub + n) * 512 + lane * 8]);
        }
#pragma unroll
        for (int h = 0; h < 2; ++h)
#pragma unroll
            for (int m = 0; m < 4; ++m)
#pragma unroll
                for (int n = 0; n < 4; ++n)
                    acc[m][n] = __builtin_amdgcn_mfma_f32_16x16x32_bf16(
                        af[h][m], bfr[h][n], acc[m][n], 0, 0, 0);
        __syncthreads();
    }

    float* Cb = (CH_P[cidx] ? part1 : part0) + (size_t)b * Tn * Tn;
    int quad = lane >> 4;
#pragma unroll
    for (int m = 0; m < 4; ++m)
#pragma unroll
        for (int n = 0; n < 4; ++n)
#pragma unroll
            for (int r = 0; r < 4; ++r) {
                int row = m0 + wmsub * 16 + m * 16 + quad * 4 + r;  // C/D: row = quad*4+reg
                int col = n0 + wnsub * 16 + n * 16 + lr;            //      col = lane&15
                Cb[(size_t)row * Tn + col] = acc[m][n][r];
            }
}

// ---------------- K2: softmax (no max shift; |a2|<0.2) over s<=t, scatter into logits ----------------
__global__ __launch_bounds__(256) void k_softscat(const float* __restrict__ part0,
                                                  const float* __restrict__ part1,
                                                  const int* __restrict__ idx,
                                                  float* __restrict__ out) {
    __shared__ float sh[Vn];
    __shared__ float red[4];
    int t = blockIdx.x, b = blockIdx.y, tid = threadIdx.x;
    int wave = tid >> 6, lane = tid & 63;
#pragma unroll
    for (int i = 0; i < Vn / 256; ++i) sh[tid + i * 256] = 0.0f;

    size_t rowoff = ((size_t)b * Tn + t) * Tn;
    int s0 = tid * 4;
    float v[4] = {0.f, 0.f, 0.f, 0.f};
    if (s0 <= t) {
        float4 v4 = *reinterpret_cast<const float4*>(&part0[rowoff + s0]);
        v[0] = v4.x; v[1] = v4.y; v[2] = v4.z; v[3] = v4.w;
        if (s0 >= 512) {  // split-K second partial exists exactly for s>=512
            float4 w4 = *reinterpret_cast<const float4*>(&part1[rowoff + s0]);
            v[0] += w4.x; v[1] += w4.y; v[2] += w4.z; v[3] += w4.w;
        }
    }
    int4 c4 = *reinterpret_cast<const int4*>(&idx[b * Tn + s0]);
    float e[4];
    float lsum = 0.f;
#pragma unroll
    for (int j = 0; j < 4; ++j) {
        e[j] = (s0 + j <= t) ? __expf(v[j]) : 0.0f;
        lsum += e[j];
    }
#pragma unroll
    for (int off = 32; off > 0; off >>= 1) lsum += __shfl_xor(lsum, off);
    if (lane == 0) red[wave] = lsum;
    __syncthreads();  // also covers sh zeroing
    float inv = 1.0f / (red[0] + red[1] + red[2] + red[3]);
    int c[4] = {c4.x, c4.y, c4.z, c4.w};
#pragma unroll
    for (int j = 0; j < 4; ++j)
        if (s0 + j <= t) atomicAdd(&sh[c[j]], e[j] * inv);
    __syncthreads();
    float* orow = out + ((size_t)b * Tn + t) * Vn;
#pragma unroll
    for (int i = 0; i < Vn / (256 * 4); ++i)
        *reinterpret_cast<float4*>(&orow[(tid + i * 256) * 4]) =
            *reinterpret_cast<const float4*>(&sh[(tid + i * 256) * 4]);
}

extern "C" void kernel_launch(void* const* d_in, const int* in_sizes, int n_in,
                              void* d_out, int out_size, void* d_ws, size_t ws_size,
                              hipStream_t stream) {
    const int* idx = (const int*)d_in[0];
    const float* vw = (const float*)d_in[1];
    const float* W = (const float*)d_in[2];
    float* out = (float*)d_out;
    char* ws = (char*)d_ws;

    __hip_bfloat16* BT = (__hip_bfloat16*)(ws);                 // 2 MB
    __hip_bfloat16* Abf = (__hip_bfloat16*)(ws + (2u << 20));   // 16 MB
    float* part0 = (float*)(ws + (18u << 20));                  // 33.6 MB
    float* part1 = (float*)(ws + (52u << 20));                  // 33.6 MB

    k_prep<<<dim3(Tn, Bn + 1), 256, 0, stream>>>(idx, W, vw, Abf, BT);
    k_gemm<<<dim3(Bn, NCHUNK), 256, 0, stream>>>(Abf, BT, part0, part1);
    k_softscat<<<dim3(Tn, Bn), 256, 0, stream>>>(part0, part1, idx, out);
}

// Round 6
// 135.502 us; speedup vs baseline: 1.1777x; 1.0058x over previous
//
#include <hip/hip_runtime.h>
#include <hip/hip_bf16.h>
#include <math.h>

#define Bn 8
#define Tn 1024
#define Vn 2048

typedef __attribute__((ext_vector_type(8))) __bf16 bf16x8;
typedef __attribute__((ext_vector_type(4))) float floatx4;

#define GLDS(gp, lp) \
    __builtin_amdgcn_global_load_lds( \
        (const __attribute__((address_space(1))) void*)(gp), \
        (__attribute__((address_space(3))) void*)(lp), 16, 0, 0)

// ---------------- K0: fused prep.
// blockIdx.y < Bn : gather  Abf[b][t][k] = bf16(W[idx[b,t], idx[b,k]]), k < kmax(t)
// blockIdx.y == Bn: BT[s][k] = (k<=s) ? bf16(exp(vw[s-k])/C[s]) : 0,  C[s]=sum_{d<=s}exp(vw[d])
__global__ __launch_bounds__(256) void k_prep(const int* __restrict__ idx,
                                              const float* __restrict__ W,
                                              const float* __restrict__ vw,
                                              __hip_bfloat16* __restrict__ Abf,
                                              __hip_bfloat16* __restrict__ BT) {
    __shared__ float sbuf[Vn];  // gather: staged W row; bt: 4-float reduction scratch
    int tid = threadIdx.x;
    if (blockIdx.y == Bn) {
        int s = blockIdx.x;
        int wave = tid >> 6, lane = tid & 63;
        float part = 0.0f;
#pragma unroll
        for (int i = 0; i < 4; ++i) {
            int d = tid + i * 256;
            if (d <= s) part += __expf(vw[d]);
        }
#pragma unroll
        for (int off = 32; off > 0; off >>= 1) part += __shfl_xor(part, off);
        if (lane == 0) sbuf[wave] = part;
        __syncthreads();
        float cinv = 1.0f / (sbuf[0] + sbuf[1] + sbuf[2] + sbuf[3]);
        int k0 = tid * 4;
        ushort u[4];
#pragma unroll
        for (int j = 0; j < 4; ++j) {
            int k = k0 + j;
            float v = (k <= s) ? __expf(vw[s - k]) * cinv : 0.0f;
            __hip_bfloat16 h = __float2bfloat16(v);
            u[j] = *reinterpret_cast<ushort*>(&h);
        }
        *reinterpret_cast<ushort4*>(&BT[(size_t)s * Tn + k0]) =
            make_ushort4(u[0], u[1], u[2], u[3]);
    } else {
        int b = blockIdx.y, t = blockIdx.x;
        int r = idx[b * Tn + t];  // block-uniform
        const float* Wr = W + (size_t)r * Vn;
#pragma unroll
        for (int i = 0; i < 2; ++i) {
            int o = (tid + i * 256) * 4;
            *reinterpret_cast<float4*>(&sbuf[o]) = *reinterpret_cast<const float4*>(&Wr[o]);
        }
        int kmax = ((t >> 7) + 1) << 7;  // GEMM never reads k >= kmax(t)
        int k0 = tid * 4;
        int4 c4 = *reinterpret_cast<const int4*>(&idx[b * Tn + k0]);
        __syncthreads();
        if (k0 < kmax) {
            ushort u[4];
            __hip_bfloat16 h;
            h = __float2bfloat16(sbuf[c4.x]); u[0] = *reinterpret_cast<ushort*>(&h);
            h = __float2bfloat16(sbuf[c4.y]); u[1] = *reinterpret_cast<ushort*>(&h);
            h = __float2bfloat16(sbuf[c4.z]); u[2] = *reinterpret_cast<ushort*>(&h);
            h = __float2bfloat16(sbuf[c4.w]); u[3] = *reinterpret_cast<ushort*>(&h);
            *reinterpret_cast<ushort4*>(&Abf[((size_t)(b * Tn + t)) * Tn + k0]) =
                make_ushort4(u[0], u[1], u[2], u[3]);
        }
    }
}

// ---------------- K1: per-b lower-triangle GEMM, K-trim + 2-way split-K,
// global_load_lds(16B) staging into fragment-ordered LDS, BK=64 ----------------
#define TM 128
#define TN 128
#define NCHUNK 46

// chunk tables, K ranges in BK=64 units, heavy-first
__device__ const signed char CH_MI[NCHUNK] = {7,7,6,7,5,6,7,4,5,6,7,3,4,5,6,7,
                                              6,7,2,3,4,5,6,7,
                                              5,6,7,1,2,3,4,5,6,7,
                                              4,5,6,7,0,1,2,3,4,5,6,7};
__device__ const signed char CH_NI[NCHUNK] = {7,7,6,6,5,5,5,4,4,4,4,3,3,3,3,3,
                                              6,6,2,2,2,2,2,2,
                                              5,5,5,1,1,1,1,1,1,1,
                                              4,4,4,4,0,0,0,0,0,0,0,0};
__device__ const signed char CH_K0[NCHUNK] = {0,8,0,0,0,0,0,0,0,0,0,0,0,0,0,0,
                                              8,8,0,0,0,0,0,0,
                                              8,8,8,0,0,0,0,0,0,0,
                                              8,8,8,8,0,0,0,0,0,0,0,0};
__device__ const signed char CH_K1[NCHUNK] = {8,16,8,8,8,8,8,8,8,8,8,8,8,8,8,8,
                                              14,14,6,6,6,6,6,6,
                                              12,12,12,4,4,4,4,4,4,4,
                                              10,10,10,10,2,2,2,2,2,2,2,2};
__device__ const signed char CH_P[NCHUNK]  = {0,1,0,0,0,0,0,0,0,0,0,0,0,0,0,0,
                                              1,1,0,0,0,0,0,0,
                                              1,1,1,0,0,0,0,0,0,0,
                                              1,1,1,1,0,0,0,0,0,0,0,0};

__global__ __launch_bounds__(256) void k_gemm(const __hip_bfloat16* __restrict__ A,
                                              const __hip_bfloat16* __restrict__ BT,
                                              float* __restrict__ part0,
                                              float* __restrict__ part1) {
    // fragment-ordered LDS: chunk c (= h*8 + sub) holds 64 lanes x 16B;
    // lane l of chunk c = X[sub*16 + (l&15)][h*32 + (l>>4)*8 .. +8)
    __shared__ __align__(16) __hip_bfloat16 As[16 * 512];  // 16 KB
    __shared__ __align__(16) __hip_bfloat16 Bs[16 * 512];  // 16 KB
    int b = blockIdx.x;  // batch fastest -> heavy chunks dispatched first
    int cidx = blockIdx.y;
    int mi = CH_MI[cidx], ni = CH_NI[cidx];
    int ki0 = CH_K0[cidx], ki1 = CH_K1[cidx];
    int m0 = mi * TM, n0 = ni * TN;
    int tid = threadIdx.x;
    int wave = tid >> 6, lane = tid & 63;
    int lr = lane & 15, lq = lane >> 4;
    int wmsub = (wave >> 1) * 4, wnsub = (wave & 1) * 4;  // fragment sub-tile bases

    const __hip_bfloat16* Ab = A + (size_t)b * Tn * Tn;

    // per-wave staging assignment: chunks 4*wave .. 4*wave+3 for both A and B
    const __hip_bfloat16* aS[4];
    const __hip_bfloat16* bS[4];
    __hip_bfloat16* aD[4];
    __hip_bfloat16* bD[4];
#pragma unroll
    for (int j = 0; j < 4; ++j) {
        int c = wave * 4 + j;
        int sub = c & 7, h = c >> 3;
        aS[j] = Ab + (size_t)(m0 + sub * 16 + lr) * Tn + h * 32 + lq * 8;
        bS[j] = BT + (size_t)(n0 + sub * 16 + lr) * Tn + h * 32 + lq * 8;
        aD[j] = &As[c * 512];
        bD[j] = &Bs[c * 512];
    }

    floatx4 acc[4][4];
#pragma unroll
    for (int i = 0; i < 4; ++i)
#pragma unroll
        for (int j = 0; j < 4; ++j) acc[i][j] = (floatx4){0.f, 0.f, 0.f, 0.f};

    for (int ki = ki0; ki < ki1; ++ki) {
        int ko = ki * 64;
#pragma unroll
        for (int j = 0; j < 4; ++j) {
            GLDS(aS[j] + ko, aD[j]);
            GLDS(bS[j] + ko, bD[j]);
        }
        __syncthreads();
        bf16x8 af[2][4], bfr[2][4];
#pragma unroll
        for (int h = 0; h < 2; ++h) {
#pragma unroll
            for (int m = 0; m < 4; ++m)
                af[h][m] = *reinterpret_cast<const bf16x8*>(
                    &As[(h * 8 + wmsub + m) * 512 + lane * 8]);
#pragma unroll
            for (int n = 0; n < 4; ++n)
                bfr[h][n] = *reinterpret_cast<const bf16x8*>(
                    &Bs[(h * 8 + wnsub + n) * 512 + lane * 8]);
        }
#pragma unroll
        for (int h = 0; h < 2; ++h)
#pragma unroll
            for (int m = 0; m < 4; ++m)
#pragma unroll
                for (int n = 0; n < 4; ++n)
                    acc[m][n] = __builtin_amdgcn_mfma_f32_16x16x32_bf16(
                        af[h][m], bfr[h][n], acc[m][n], 0, 0, 0);
        __syncthreads();
    }

    float* Cb = (CH_P[cidx] ? part1 : part0) + (size_t)b * Tn * Tn;
    int quad = lane >> 4;
#pragma unroll
    for (int m = 0; m < 4; ++m)
#pragma unroll
        for (int n = 0; n < 4; ++n)
#pragma unroll
            for (int r = 0; r < 4; ++r) {
                int row = m0 + wmsub * 16 + m * 16 + quad * 4 + r;  // C/D: row = quad*4+reg
                int col = n0 + wnsub * 16 + n * 16 + lr;            //      col = lane&15
                Cb[(size_t)row * Tn + col] = acc[m][n][r];
            }
}

// ---------------- K2: softmax (no max shift; |a2|<0.2) over s<=t, scatter into logits ----------------
__global__ __launch_bounds__(256) void k_softscat(const float* __restrict__ part0,
                                                  const float* __restrict__ part1,
                                                  const int* __restrict__ idx,
                                                  float* __restrict__ out) {
    __shared__ float sh[Vn];
    __shared__ float red[4];
    int t = blockIdx.x, b = blockIdx.y, tid = threadIdx.x;
    int wave = tid >> 6, lane = tid & 63;
#pragma unroll
    for (int i = 0; i < Vn / 256; ++i) sh[tid + i * 256] = 0.0f;

    size_t rowoff = ((size_t)b * Tn + t) * Tn;
    int s0 = tid * 4;
    float v[4] = {0.f, 0.f, 0.f, 0.f};
    if (s0 <= t) {
        float4 v4 = *reinterpret_cast<const float4*>(&part0[rowoff + s0]);
        v[0] = v4.x; v[1] = v4.y; v[2] = v4.z; v[3] = v4.w;
        if (s0 >= 512) {  // split-K second partial exists exactly for s>=512
            float4 w4 = *reinterpret_cast<const float4*>(&part1[rowoff + s0]);
            v[0] += w4.x; v[1] += w4.y; v[2] += w4.z; v[3] += w4.w;
        }
    }
    int4 c4 = *reinterpret_cast<const int4*>(&idx[b * Tn + s0]);
    float e[4];
    float lsum = 0.f;
#pragma unroll
    for (int j = 0; j < 4; ++j) {
        e[j] = (s0 + j <= t) ? __expf(v[j]) : 0.0f;
        lsum += e[j];
    }
#pragma unroll
    for (int off = 32; off > 0; off >>= 1) lsum += __shfl_xor(lsum, off);
    if (lane == 0) red[wave] = lsum;
    __syncthreads();  // also covers sh zeroing
    float inv = 1.0f / (red[0] + red[1] + red[2] + red[3]);
    int c[4] = {c4.x, c4.y, c4.z, c4.w};
#pragma unroll
    for (int j = 0; j < 4; ++j)
        if (s0 + j <= t) atomicAdd(&sh[c[j]], e[j] * inv);
    __syncthreads();
    float* orow = out + ((size_t)b * Tn + t) * Vn;
#pragma unroll
    for (int i = 0; i < Vn / (256 * 4); ++i) {
        floatx4 val = *reinterpret_cast<const floatx4*>(&sh[(tid + i * 256) * 4]);
        __builtin_nontemporal_store(val,
            reinterpret_cast<floatx4*>(&orow[(tid + i * 256) * 4]));
    }
}

extern "C" void kernel_launch(void* const* d_in, const int* in_sizes, int n_in,
                              void* d_out, int out_size, void* d_ws, size_t ws_size,
                              hipStream_t stream) {
    const int* idx = (const int*)d_in[0];
    const float* vw = (const float*)d_in[1];
    const float* W = (const float*)d_in[2];
    float* out = (float*)d_out;
    char* ws = (char*)d_ws;

    __hip_bfloat16* BT = (__hip_bfloat16*)(ws);                 // 2 MB
    __hip_bfloat16* Abf = (__hip_bfloat16*)(ws + (2u << 20));   // 16 MB
    float* part0 = (float*)(ws + (18u << 20));                  // 33.6 MB
    float* part1 = (float*)(ws + (52u << 20));                  // 33.6 MB

    k_prep<<<dim3(Tn, Bn + 1), 256, 0, stream>>>(idx, W, vw, Abf, BT);
    k_gemm<<<dim3(Bn, NCHUNK), 256, 0, stream>>>(Abf, BT, part0, part1);
    k_softscat<<<dim3(Tn, Bn), 256, 0, stream>>>(part0, part1, idx, out);
}